// Round 8
// baseline (88.321 us; speedup 1.0000x reference)
//
#include <hip/hip_runtime.h>

typedef unsigned long long u64;

#define S_LEN 2048
#define BATCH 8
#define NTOK 64
#define DMODEL 648
#define NBLK 32   // 32 blocks of 64 positions

// Workspace (u64 units):
//   T1 [BATCH][2048] @ 0     : S1 rows.  bit jj of T1[b][w*64+t] = (src[64w+jj-1]==t)
//   LP [BATCH][2048] @ 16384 : P rows.   bit jj of LP[b][w*64+t] = (src[64w+jj]==t)
//   sT [BATCH][S_LEN]@ 32768 : transposed src (int)
// Depth-d rows derive from S1: S_d[w][t] = (S1[w][t]<<(d-1)) | (S1[w-1][t]>>(65-d)).

__global__ __launch_bounds__(256) void build_kernel(const int* __restrict__ src,
                                                    u64* __restrict__ T1,
                                                    u64* __restrict__ LP,
                                                    int* __restrict__ sT) {
    const int b = blockIdx.y;
    const int w = blockIdx.x * 4 + (threadIdx.x >> 6);
    const int lane = threadIdx.x & 63;
    const int p = (w << 6) + lane;
    const int tok  = src[p * BATCH + b];
    const int tokp = (w > 0) ? src[(p - 64) * BATCH + b] : -1;  // prev block
    u64 m_sel = 0, mp_sel = 0;
    #pragma unroll 8
    for (int t = 0; t < NTOK; ++t) {
        const u64 m  = __ballot(tok == t);
        const u64 mp = __ballot(tokp == t);
        if (lane == t) { m_sel = m; mp_sel = mp; }
    }
    const int idx = b * 2048 + (w << 6) + lane;   // lane == token slot
    LP[idx] = m_sel;
    T1[idx] = (m_sel << 1) | (mp_sel >> 63);
    sT[b * S_LEN + p] = tok;
}

// ---------------------------------------------------------------------------
// Compute: WG = 256 thr = 4 waves, LDS 32 KiB -> 4 WG/CU; grid 1024 WGs ->
// ALL resident, 16 waves/CU (4/SIMD). Each wave: pair-units {u, 1023-u}
// (queries {2u,2u+1} and mirror) -> ~33 balanced block-iters per wave.
// Lane = token id. Inner loop is LDS-only:
//   pv   = LP[w][lane]                     (per-lane, 2-way free)
//   c_i  = S1[w][tk[i]] (broadcast reads, i=1..5), p_i = prev block's c_i
//   r=0 (q=q0):  A1=c4&pv; A2=A1&f(c3,p3,1); A3=A2&f(c2,p2,2); A4=A3&f(c1,p1,3)
//   r=1 (q=q0+1):A1=c5&pv; A2=A1&f(c4,p4,1); A3=A2&f(c3,p3,2); A4=A3&f(c2,p2,3)
//   where f(c,p,k) = (c<<k)|(p>>(64-k));  h_d += popc(A_d)
//   c_d = wave-sum h_d (epilogue packed shfl reduce); cu += popc(pv).
// ---------------------------------------------------------------------------
__global__ __launch_bounds__(256, 4) void compute_kernel(const u64* __restrict__ T1,
                                                         const u64* __restrict__ LP,
                                                         const int* __restrict__ sT,
                                                         float* __restrict__ out) {
    __shared__ __align__(16) u64 LT[2048];   // 16 KiB S1 table
    __shared__ __align__(16) u64 LL[2048];   // 16 KiB P  table

    const int b = blockIdx.y;
    const int tid = threadIdx.x;
    const int lane = tid & 63;
    const int wv = tid >> 6;

    {   // stage tables (16B vector copies)
        const ulonglong2* G1 = (const ulonglong2*)(T1 + (size_t)b * 2048);
        const ulonglong2* G2 = (const ulonglong2*)(LP + (size_t)b * 2048);
        ulonglong2* D1 = (ulonglong2*)LT;
        ulonglong2* D2 = (ulonglong2*)LL;
        #pragma unroll
        for (int i = tid; i < 1024; i += 256) { D1[i] = G1[i]; D2[i] = G2[i]; }
    }
    __syncthreads();

    const int uw = blockIdx.x * 4 + wv;   // 0..511 per b
    const int* s = sT + b * S_LEN;

    #pragma unroll 1
    for (int half = 0; half < 2; ++half) {
        const int u = half ? (1023 - uw) : uw;   // pair-unit id, 0..1023
        const int q0 = u << 1;                   // even; queries q0, q0+1

        int tk[6];
        #pragma unroll
        for (int i = 0; i < 6; ++i) {
            const int idx = q0 - 4 + i;
            tk[i] = (idx >= 0) ? s[idx] : 0;     // clamp: provably-dead rows
        }

        int h1a = 0, h2a = 0, h3a = 0, h4a = 0;
        int h1b = 0, h2b = 0, h3b = 0, h4b = 0;
        int cuF = 0, cu0, cu1;
        const int wq = q0 >> 6, rem0 = q0 & 63;

        u64 p1_ = 0, p2_ = 0, p3_ = 0, p4_ = 0;   // prev-block S1 rows

        for (int w = 0; w < wq; ++w) {
            const int wb = w << 6;
            const u64 pv  = LL[wb + lane];
            const u64 c1_ = LT[wb + tk[1]];
            const u64 c2_ = LT[wb + tk[2]];
            const u64 c3_ = LT[wb + tk[3]];
            const u64 c4_ = LT[wb + tk[4]];
            const u64 c5_ = LT[wb + tk[5]];
            cuF += __popcll(pv);
            {   // r = 0 (q = q0)
                const u64 A1 = c4_ & pv;
                const u64 A2 = A1 & ((c3_ << 1) | (p3_ >> 63));
                const u64 A3 = A2 & ((c2_ << 2) | (p2_ >> 62));
                const u64 A4 = A3 & ((c1_ << 3) | (p1_ >> 61));
                h1a += __popcll(A1); h2a += __popcll(A2);
                h3a += __popcll(A3); h4a += __popcll(A4);
            }
            {   // r = 1 (q = q0+1)
                const u64 A1 = c5_ & pv;
                const u64 A2 = A1 & ((c4_ << 1) | (p4_ >> 63));
                const u64 A3 = A2 & ((c3_ << 2) | (p3_ >> 62));
                const u64 A4 = A3 & ((c2_ << 3) | (p2_ >> 61));
                h1b += __popcll(A1); h2b += __popcll(A2);
                h3b += __popcll(A3); h4b += __popcll(A4);
            }
            p1_ = c1_; p2_ = c2_; p3_ = c3_; p4_ = c4_;
        }

        {   // final block w = wq (valid j-bits only)
            const int wb = wq << 6;
            const u64 pv  = LL[wb + lane];
            const u64 c1_ = LT[wb + tk[1]];
            const u64 c2_ = LT[wb + tk[2]];
            const u64 c3_ = LT[wb + tk[3]];
            const u64 c4_ = LT[wb + tk[4]];
            const u64 c5_ = LT[wb + tk[5]];
            const u64 v0 = (1ull << rem0) - 1ull;   // j < q0   (rem0 may be 0)
            const u64 v1 = (2ull << rem0) - 1ull;   // j < q0+1 (rem0 <= 62)
            cu0 = cuF + __popcll(pv & v0);
            cu1 = cuF + __popcll(pv & v1);
            {   // r = 0
                const u64 A1 = c4_ & pv & v0;
                const u64 A2 = A1 & ((c3_ << 1) | (p3_ >> 63));
                const u64 A3 = A2 & ((c2_ << 2) | (p2_ >> 62));
                const u64 A4 = A3 & ((c1_ << 3) | (p1_ >> 61));
                h1a += __popcll(A1); h2a += __popcll(A2);
                h3a += __popcll(A3); h4a += __popcll(A4);
            }
            {   // r = 1
                const u64 A1 = c5_ & pv & v1;
                const u64 A2 = A1 & ((c4_ << 1) | (p4_ >> 63));
                const u64 A3 = A2 & ((c3_ << 2) | (p3_ >> 62));
                const u64 A4 = A3 & ((c2_ << 3) | (p2_ >> 61));
                h1b += __popcll(A1); h2b += __popcll(A2);
                h3b += __popcll(A3); h4b += __popcll(A4);
            }
        }

        // Epilogue per query: c_d = wave-sum of h_d (packed), write 648 chans.
        #pragma unroll
        for (int r = 0; r < 2; ++r) {
            const int q = q0 + r;
            const int hh1 = r ? h1b : h1a, hh2 = r ? h2b : h2a;
            const int hh3 = r ? h3b : h3a, hh4 = r ? h4b : h4a;
            const int cuq = r ? cu1 : cu0;
            int p01 = hh1 | (hh2 << 16);
            int p23 = hh3 | (hh4 << 16);
            #pragma unroll
            for (int sft = 1; sft < 64; sft <<= 1) {
                p01 += __shfl_xor(p01, sft);
                p23 += __shfl_xor(p23, sft);
            }
            const int c1 = p01 & 0xffff, c2 = p01 >> 16;
            const int c3 = p23 & 0xffff, c4 = p23 >> 16;

            float* op = out + ((size_t)q * BATCH + b) * DMODEL;
            #pragma unroll
            for (int m = 0; m <= 4; ++m) {   // one-hot blocks, sentinel -> 0
                const bool sent = (q - m) < 0;
                op[m * 64 + lane] = (!sent && lane == tk[4 + r - m]) ? 1.f : 0.f;
            }
            op[320 + lane] = (float)hh1 / (float)(c1 ? c1 : 1);
            op[384 + lane] = (float)hh2 / (float)(c2 ? c2 : 1);
            op[448 + lane] = (float)hh3 / (float)(c3 ? c3 : 1);
            op[512 + lane] = (float)hh4 / (float)(c4 ? c4 : 1);
            op[576 + lane] = (float)cuq / (float)(q ? q : 1);
            if (lane < 8) {
                float v = 0.f;
                if (lane == 0) v = (float)c1;
                else if (lane == 1) v = (float)c2;
                else if (lane == 2) v = (float)c3;
                else if (lane == 3) v = (float)c4;
                else if (lane == 4) v = (float)q;
                op[640 + lane] = v;
            }
        }
    }
}

extern "C" void kernel_launch(void* const* d_in, const int* in_sizes, int n_in,
                              void* d_out, int out_size, void* d_ws, size_t ws_size,
                              hipStream_t stream) {
    const int* src = (const int*)d_in[0];
    float* out = (float*)d_out;
    u64* T1 = (u64*)d_ws;            // 16384 u64
    u64* LP = T1 + 16384;            // 16384 u64
    int* sT = (int*)(T1 + 32768);    // 16384 int

    build_kernel<<<dim3(8, BATCH), 256, 0, stream>>>(src, T1, LP, sT);
    // 512 wave-tasks per b / 4 waves per WG -> grid (128, 8) = 1024 WGs (4/CU)
    compute_kernel<<<dim3(128, BATCH), 256, 0, stream>>>(T1, LP, sT, out);
}

// Round 9
// 85.596 us; speedup vs baseline: 1.0318x; 1.0318x over previous
//
#include <hip/hip_runtime.h>

typedef unsigned long long u64;
typedef unsigned int u32;
typedef unsigned short u16;
typedef unsigned char u8;

#define S_LEN 2048
#define BATCH 8
#define DMODEL 648
#define NBLK 32   // 32 blocks of 64 positions

// Workspace byte offsets:
//  PAIR ulonglong2[8][2048] @ 0       {S1,S2} rows: S1 bit jj = (src[64w+jj-1]==t), S2 = shift 2
//  PG   u64[8][2048]        @ 512K    P rows: bit jj = (src[64w+jj]==t)
//  PB   u16[8][32][4096]    @ 640K    excl-prefix bigram counts: #{j<64c: src[j-1]==t0 && src[j]==t}
//  PU   u16[8][32][64]      @ 2688K   excl-prefix unigram:       #{j<64c: src[j]==t}
//  PS1  u16[8][32][64]      @ 2720K   excl-prefix popc(S1):      #{j<64c: src[j-1]==t0}
//  RB   u32[8][64][64]      @ 2752K   RB[x][y] bit w = exists j in block w: src[j-2]==x && src[j-1]==y
//  SRC8 u8[8][2048]         @ 2880K   transposed src (u8)

// ---------------------------------------------------------------------------
// K1: per (block w, batch b) wave. Ballot-build P and {S1,S2} pair rows.
// ---------------------------------------------------------------------------
__global__ __launch_bounds__(64) void k1_rows(const int* __restrict__ src,
                                              ulonglong2* __restrict__ PAIR,
                                              u64* __restrict__ PG,
                                              u8* __restrict__ SRC8) {
    const int w = blockIdx.x, b = blockIdx.y;
    const int lane = threadIdx.x;
    const int p = (w << 6) + lane;
    const int tok  = src[p * BATCH + b];
    const int tokp = (w > 0) ? src[(p - 64) * BATCH + b] : -1;
    u64 m_sel = 0, mp_sel = 0;
    #pragma unroll 8
    for (int t = 0; t < 64; ++t) {
        const u64 m  = __ballot(tok == t);
        const u64 mp = __ballot(tokp == t);
        if (lane == t) { m_sel = m; mp_sel = mp; }
    }
    const int idx = b * 2048 + (w << 6) + lane;   // lane == token slot
    PG[idx] = m_sel;
    ulonglong2 pr;
    pr.x = (m_sel << 1) | (mp_sel >> 63);   // S1
    pr.y = (m_sel << 2) | (mp_sel >> 62);   // S2
    PAIR[idx] = pr;
    SRC8[b * 2048 + p] = (u8)tok;
}

// ---------------------------------------------------------------------------
// K2: prefix tables + rare-block bitmap. One wave per (x=t0-role, b);
// lane = second token. 32 sequential block iters per wave.
// ---------------------------------------------------------------------------
__global__ __launch_bounds__(256) void k2_tables(const ulonglong2* __restrict__ PAIR,
                                                 const u64* __restrict__ PG,
                                                 u16* __restrict__ PB,
                                                 u16* __restrict__ PU,
                                                 u16* __restrict__ PS1,
                                                 u32* __restrict__ RB) {
    const int b = blockIdx.y;
    const int x = blockIdx.x * 4 + (threadIdx.x >> 6);  // 0..63
    const int lane = threadIdx.x & 63;
    const int base = b * 2048;

    u32 cntPB = 0;    // per-lane: bigram (x, lane) prefix
    u32 pu = 0;       // per-lane (only x==0 wave writes)
    u32 ps1 = 0;      // uniform
    u32 rb = 0;       // per-lane: bigram (x@j-2, lane@j-1) presence per block
    for (int w = 0; w < NBLK; ++w) {
        const int i0 = base + (w << 6);
        const ulonglong2 pr = PAIR[i0 + x];     // uniform row (S1[x], S2[x])
        const u64 pv  = PG[i0 + lane];          // per-lane P row
        const u64 s1l = PAIR[i0 + lane].x;      // per-lane S1 row
        PB[(size_t)(b * NBLK + w) * 4096 + (x << 6) + lane] = (u16)cntPB;
        cntPB += (u32)__popcll(pr.x & pv);
        if (x == 0) PU[(b * NBLK + w) * 64 + lane] = (u16)pu;
        pu += (u32)__popcll(pv);
        if (lane == 0) PS1[(b * NBLK + w) * 64 + x] = (u16)ps1;
        ps1 += (u32)__popcll(pr.x);
        rb |= ((pr.y & s1l) != 0ull ? 1u : 0u) << w;
    }
    RB[(b << 12) + (x << 6) + lane] = rb;
}

// ---------------------------------------------------------------------------
// K3: one wave per 4 consecutive queries. O(1) per query + rare blocks.
// Lane = token id.
// ---------------------------------------------------------------------------
__global__ __launch_bounds__(256, 4) void k3_compute(const ulonglong2* __restrict__ PAIR,
                                                     const u64* __restrict__ PG,
                                                     const u16* __restrict__ PB,
                                                     const u16* __restrict__ PU,
                                                     const u16* __restrict__ PS1,
                                                     const u32* __restrict__ RB,
                                                     const u8* __restrict__ SRC8,
                                                     float* __restrict__ out) {
    __shared__ __align__(16) ulonglong2 Lpair[2048];  // 32 KB
    __shared__ u8 Lsrc[2048];                         // 2 KB

    const int b = blockIdx.y;
    const int tid = threadIdx.x;
    const int lane = tid & 63;
    const int wv = tid >> 6;

    {
        const ulonglong2* G = PAIR + b * 2048;
        for (int i = tid; i < 2048; i += 256) Lpair[i] = G[i];
        ((u64*)Lsrc)[tid] = ((const u64*)(SRC8 + b * 2048))[tid & 255];
    }
    __syncthreads();

    const u64* PGb  = PG + b * 2048;
    const u16* PBb  = PB + (size_t)b * NBLK * 4096;
    const u16* PUb  = PU + b * NBLK * 64;
    const u16* PS1b = PS1 + b * NBLK * 64;
    const u32* RBb  = RB + (b << 12);

    const int uq = blockIdx.x * 4 + wv;   // 0..511
    const int q0 = uq << 2;

    int tk[8];
    #pragma unroll
    for (int i = 0; i < 8; ++i) {
        const int idx = q0 - 4 + i;
        tk[i] = (idx >= 0) ? (int)Lsrc[idx] : 0;   // clamp: provably-dead rows
    }

    #pragma unroll
    for (int r = 0; r < 4; ++r) {
        const int q = q0 + r;
        const int t0 = tk[4 + r], t1 = tk[3 + r], t2 = tk[2 + r], t3 = tk[1 + r];
        const int cq = q >> 6, rem = q & 63;
        const int cbase = cq << 6;
        const u64 valid = (1ull << rem) - 1ull;

        const ulonglong2 pa = Lpair[cbase + t0];
        const ulonglong2 pbq = Lpair[cbase + t1];
        const u64 M1p = pa.x & valid;

        int c1 = (int)PS1b[cbase + t0] + __popcll(M1p);
        int h1 = (int)PBb[((size_t)cq << 12) + (t0 << 6) + lane];
        int cu = (int)PUb[cbase + lane];
        const u64 pvq = PGb[cbase + lane];
        cu += __popcll(pvq & valid);

        u64 mrem = M1p;                    // sparse in-chunk depth-1 updates
        while (mrem) {
            const int jj = __builtin_ctzll(mrem);
            mrem &= mrem - 1;
            const int tj = (int)Lsrc[cbase + jj];
            h1 += (lane == tj) ? 1 : 0;
        }

        int c2 = 0, c3 = 0, c4 = 0, h2 = 0, h3 = 0, h4 = 0;
        const u64 M2p = M1p & pbq.y;
        if (M2p) {   // final partial block, depths 2..4 (uniform branch, rare)
            const u64 cS2  = Lpair[cbase + t2].y;
            const u64 cS2p = cq ? Lpair[cbase - 64 + t2].y : 0ull;
            const u64 dS2  = Lpair[cbase + t3].y;
            const u64 dS2p = cq ? Lpair[cbase - 64 + t3].y : 0ull;
            const u64 M3p = M2p & ((cS2 << 1) | (cS2p >> 63));
            const u64 M4p = M3p & ((dS2 << 2) | (dS2p >> 62));
            c2 += __popcll(M2p); h2 += __popcll(M2p & pvq);
            c3 += __popcll(M3p); h3 += __popcll(M3p & pvq);
            c4 += __popcll(M4p); h4 += __popcll(M4p & pvq);
        }
        u32 rare = RBb[(t1 << 6) + t0] & ((1u << cq) - 1u);  // full blocks w<cq
        while (rare) {   // E ~0.25 blocks/query
            const int w = __builtin_ctz(rare);
            rare &= rare - 1;
            const int wb = w << 6;
            const u64 M2 = Lpair[wb + t0].x & Lpair[wb + t1].y;
            const u64 cS2  = Lpair[wb + t2].y;
            const u64 cS2p = w ? Lpair[wb - 64 + t2].y : 0ull;
            const u64 dS2  = Lpair[wb + t3].y;
            const u64 dS2p = w ? Lpair[wb - 64 + t3].y : 0ull;
            const u64 M3 = M2 & ((cS2 << 1) | (cS2p >> 63));
            const u64 M4 = M3 & ((dS2 << 2) | (dS2p >> 62));
            const u64 pvw = PGb[wb + lane];
            c2 += __popcll(M2); h2 += __popcll(M2 & pvw);
            c3 += __popcll(M3); h3 += __popcll(M3 & pvw);
            c4 += __popcll(M4); h4 += __popcll(M4 & pvw);
        }

        float* op = out + ((size_t)q * BATCH + b) * DMODEL;
        #pragma unroll
        for (int m = 0; m <= 4; ++m) {   // one-hot blocks, sentinel -> zeros
            const bool sent = (q - m) < 0;
            op[m * 64 + lane] = (!sent && lane == tk[4 + r - m]) ? 1.f : 0.f;
        }
        op[320 + lane] = (float)h1 / (float)(c1 ? c1 : 1);
        op[384 + lane] = (float)h2 / (float)(c2 ? c2 : 1);
        op[448 + lane] = (float)h3 / (float)(c3 ? c3 : 1);
        op[512 + lane] = (float)h4 / (float)(c4 ? c4 : 1);
        op[576 + lane] = (float)cu / (float)(q ? q : 1);
        if (lane < 8) {
            float v = 0.f;
            if (lane == 0) v = (float)c1;
            else if (lane == 1) v = (float)c2;
            else if (lane == 2) v = (float)c3;
            else if (lane == 3) v = (float)c4;
            else if (lane == 4) v = (float)q;
            op[640 + lane] = v;
        }
    }
}

extern "C" void kernel_launch(void* const* d_in, const int* in_sizes, int n_in,
                              void* d_out, int out_size, void* d_ws, size_t ws_size,
                              hipStream_t stream) {
    const int* src = (const int*)d_in[0];
    float* out = (float*)d_out;
    char* ws = (char*)d_ws;
    ulonglong2* PAIR = (ulonglong2*)(ws);
    u64* PG   = (u64*)(ws + (512u << 10));
    u16* PB   = (u16*)(ws + (640u << 10));
    u16* PU   = (u16*)(ws + (2688u << 10));
    u16* PS1  = (u16*)(ws + (2720u << 10));
    u32* RB   = (u32*)(ws + (2752u << 10));
    u8*  SRC8 = (u8*)(ws + (2880u << 10));

    k1_rows<<<dim3(NBLK, BATCH), 64, 0, stream>>>(src, PAIR, PG, SRC8);
    k2_tables<<<dim3(16, BATCH), 256, 0, stream>>>(PAIR, PG, PB, PU, PS1, RB);
    k3_compute<<<dim3(128, BATCH), 256, 0, stream>>>(PAIR, PG, PB, PU, PS1, RB, SRC8, out);
}

// Round 10
// 81.639 us; speedup vs baseline: 1.0818x; 1.0485x over previous
//
#include <hip/hip_runtime.h>

typedef unsigned long long u64;
typedef unsigned int u32;
typedef unsigned short u16;
typedef unsigned char u8;

#define S_LEN 2048
#define BATCH 8
#define DMODEL 648
#define NBLK 32   // 32 blocks of 64 positions

// Workspace byte offsets:
//  PAIR ulonglong2[8][2048] @ 0      {S1,S2}: S1 bit jj=(src[64w+jj-1]==t), S2 shift 2
//  PG   u64[8][2048]  @ 256K   P rows: bit jj = (src[64w+jj]==t)
//  PB   u16[8][32][4096] @ 384K  excl-prefix bigram: #{j<64c: src[j-1]==t0 && src[j]==t}
//  PU   u16[8][32][64]   @ 2432K excl-prefix unigram: #{j<64c: src[j]==t}
//  PS1  u16[8][32][64]   @ 2464K excl-prefix: #{j<64c: src[j-1]==t0}
//  RB   u32[8][64][64]   @ 2496K RB[x][y] bit w = exists j in blk w: src[j-2]==x && src[j-1]==y
//  SRC8 u8[8][2048]      @ 2624K transposed src (u8)

// ---------------------------------------------------------------------------
// K12: grid (8, BATCH) x 256. Each WG: build P (atomicOr in LDS) + pair rows,
// then scan 8 x-values (2 per wave) producing prefix tables + rare bitmap.
// WG gx==0 also publishes PAIR/PG/SRC8 to global for K3.
// ---------------------------------------------------------------------------
__global__ __launch_bounds__(256) void k12_build(const int* __restrict__ src,
                                                 ulonglong2* __restrict__ PAIR,
                                                 u64* __restrict__ PG,
                                                 u16* __restrict__ PB,
                                                 u16* __restrict__ PU,
                                                 u16* __restrict__ PS1,
                                                 u32* __restrict__ RB,
                                                 u8* __restrict__ SRC8) {
    __shared__ __align__(16) ulonglong2 Lpair[2048];  // 32 KB
    __shared__ u64 LP[2048];                          // 16 KB

    const int b = blockIdx.y, gx = blockIdx.x;        // gx 0..7
    const int tid = threadIdx.x, lane = tid & 63, wv = tid >> 6;

    int myt[8];
    #pragma unroll
    for (int k = 0; k < 8; ++k) {
        const int i = tid + 256 * k;
        myt[k] = src[i * BATCH + b];
        LP[i] = 0;
    }
    __syncthreads();
    #pragma unroll
    for (int k = 0; k < 8; ++k) {
        const int i = tid + 256 * k;
        atomicOr(&LP[(i & ~63) | myt[k]], 1ull << (i & 63));
    }
    __syncthreads();
    #pragma unroll
    for (int k = 0; k < 8; ++k) {
        const int i = tid + 256 * k;
        const u64 m = LP[i];
        const u64 mp = (i >= 64) ? LP[i - 64] : 0ull;
        ulonglong2 pr;
        pr.x = (m << 1) | (mp >> 63);
        pr.y = (m << 2) | (mp >> 62);
        Lpair[i] = pr;
        if (gx == 0) {
            PG[b * 2048 + i] = m;
            PAIR[b * 2048 + i] = pr;
            SRC8[b * 2048 + i] = (u8)myt[k];
        }
    }
    __syncthreads();

    #pragma unroll 1
    for (int j = 0; j < 2; ++j) {
        const int x = gx * 8 + wv * 2 + j;   // 0..63
        u32 cnt = 0, ps1 = 0, rb = 0, pu = 0;
        for (int w = 0; w < NBLK; ++w) {
            const int wb = w << 6;
            const ulonglong2 prx = Lpair[wb + x];   // uniform broadcast
            const u64 pvl = LP[wb + lane];          // per-lane
            const u64 s1l = Lpair[wb + lane].x;     // per-lane
            PB[(size_t)(b * NBLK + w) * 4096 + (x << 6) + lane] = (u16)cnt;
            cnt += (u32)__popcll(prx.x & pvl);
            if (x == 0) { PU[(b * NBLK + w) * 64 + lane] = (u16)pu; pu += (u32)__popcll(pvl); }
            if (lane == 0) PS1[(b * NBLK + w) * 64 + x] = (u16)ps1;
            ps1 += (u32)__popcll(prx.x);
            rb |= ((prx.y & s1l) != 0ull ? 1u : 0u) << w;
        }
        RB[(b << 12) + (x << 6) + lane] = rb;
    }
}

// ---------------------------------------------------------------------------
// K3: ZERO LDS, one wave per 2 queries {2u, 2u+1}. Lane = token id.
// O(1) per query via prefix tables; depths 2-4 only touch blocks flagged in RB
// (E ~0.25 blocks/query). h-updates use h += popc(M & P[·][lane]) (no loops).
// ---------------------------------------------------------------------------
__global__ __launch_bounds__(256) void k3_compute(const ulonglong2* __restrict__ PAIR,
                                                  const u64* __restrict__ PG,
                                                  const u16* __restrict__ PB,
                                                  const u16* __restrict__ PU,
                                                  const u16* __restrict__ PS1,
                                                  const u32* __restrict__ RB,
                                                  const u8* __restrict__ SRC8,
                                                  float* __restrict__ out) {
    const int b = blockIdx.y;
    const int tid = threadIdx.x, lane = tid & 63, wv = tid >> 6;
    const int u = blockIdx.x * 4 + wv;   // 0..1023
    const int q0 = u << 1;               // even

    const ulonglong2* PAb = PAIR + b * 2048;
    const u64* PGb  = PG + b * 2048;
    const u16* PBb  = PB + (size_t)b * NBLK * 4096;
    const u16* PUb  = PU + b * 2048;
    const u16* PS1b = PS1 + b * 2048;
    const u32* RBb  = RB + (b << 12);

    // tokens q0-4 .. q0+1 from one aligned 16B window
    const int base = (q0 >= 4) ? (q0 - 4) : 0;
    const u64* sp = (const u64*)(SRC8 + b * 2048 + (base & ~7));
    const u64 lo = sp[0], hi = sp[1];
    const int o = (base & 7) * 8;
    const u64 tb = o ? ((lo >> o) | (hi << (64 - o))) : lo;
    int tk[6];
    #pragma unroll
    for (int i = 0; i < 6; ++i) {
        const int idx = q0 - 4 + i;
        const int bix = idx - base;
        const int sh = (bix > 0 ? bix : 0) * 8;
        tk[i] = (idx >= 0) ? (int)((tb >> sh) & 0xFF) : 0;  // clamp: dead rows
    }

    const int cq = q0 >> 6, rem0 = q0 & 63;
    const int cbase = cq << 6;
    const u64 v0 = (1ull << rem0) - 1ull;   // j < q0
    const u64 v1 = (2ull << rem0) - 1ull;   // j < q0+1 (rem0 <= 62)

    const u64 pvq = PGb[cbase + lane];
    const int puq = (int)PUb[cbase + lane];
    const ulonglong2 A = PAb[cbase + tk[4]];             // .x M1row r0, .y S2row r1
    const u64 B1 = PAb[cbase + tk[5]].x;                 // M1row r1
    const u64 C2 = ((const u64*)&PAb[cbase + tk[3]])[1]; // S2row r0
    const int ps1_[2] = {(int)PS1b[cbase + tk[4]], (int)PS1b[cbase + tk[5]]};
    const int hb_[2]  = {(int)PBb[((size_t)cq << 12) + (tk[4] << 6) + lane],
                         (int)PBb[((size_t)cq << 12) + (tk[5] << 6) + lane]};
    const u32 rbm = (1u << cq) - 1u;
    const u32 rare_[2] = {RBb[(tk[3] << 6) + tk[4]] & rbm,
                          RBb[(tk[4] << 6) + tk[5]] & rbm};
    const u64 M1row_[2] = {A.x, B1};
    const u64 S2row_[2] = {C2, A.y};
    const u64 vv_[2] = {v0, v1};

    #pragma unroll
    for (int r = 0; r < 2; ++r) {
        const int q = q0 + r;
        const int t0 = tk[4 + r], t1 = tk[3 + r], t2 = tk[2 + r], t3 = tk[1 + r];
        const u64 valid = vv_[r];

        const u64 M1p = M1row_[r] & valid;
        int c1 = ps1_[r] + __popcll(M1p);
        int h1 = hb_[r] + __popcll(M1p & pvq);
        int cu = puq + __popcll(pvq & valid);

        int c2 = 0, c3 = 0, c4 = 0, h2 = 0, h3 = 0, h4 = 0;
        const u64 M2p = M1p & S2row_[r];
        if (M2p) {   // partial-chunk depths 2-4 (uniform, rare)
            const u64 cS2  = ((const u64*)&PAb[cbase + t2])[1];
            const u64 cS2p = cq ? ((const u64*)&PAb[cbase - 64 + t2])[1] : 0ull;
            const u64 dS2  = ((const u64*)&PAb[cbase + t3])[1];
            const u64 dS2p = cq ? ((const u64*)&PAb[cbase - 64 + t3])[1] : 0ull;
            const u64 M3p = M2p & ((cS2 << 1) | (cS2p >> 63));
            const u64 M4p = M3p & ((dS2 << 2) | (dS2p >> 62));
            c2 += __popcll(M2p); h2 += __popcll(M2p & pvq);
            c3 += __popcll(M3p); h3 += __popcll(M3p & pvq);
            c4 += __popcll(M4p); h4 += __popcll(M4p & pvq);
        }
        u32 rare = rare_[r];   // full blocks w < cq containing the bigram
        while (rare) {
            const int w = __builtin_ctz(rare);
            rare &= rare - 1;
            const int wb = w << 6;
            const u64 M2 = PAb[wb + t0].x & ((const u64*)&PAb[wb + t1])[1];
            const u64 cS2  = ((const u64*)&PAb[wb + t2])[1];
            const u64 cS2p = w ? ((const u64*)&PAb[wb - 64 + t2])[1] : 0ull;
            const u64 dS2  = ((const u64*)&PAb[wb + t3])[1];
            const u64 dS2p = w ? ((const u64*)&PAb[wb - 64 + t3])[1] : 0ull;
            const u64 M3 = M2 & ((cS2 << 1) | (cS2p >> 63));
            const u64 M4 = M3 & ((dS2 << 2) | (dS2p >> 62));
            const u64 pvw = PGb[wb + lane];
            c2 += __popcll(M2); h2 += __popcll(M2 & pvw);
            c3 += __popcll(M3); h3 += __popcll(M3 & pvw);
            c4 += __popcll(M4); h4 += __popcll(M4 & pvw);
        }

        float* op = out + ((size_t)q * BATCH + b) * DMODEL;
        #pragma unroll
        for (int m = 0; m <= 4; ++m) {   // one-hot blocks, sentinel -> zeros
            const bool sent = (q - m) < 0;
            op[m * 64 + lane] = (!sent && lane == tk[4 + r - m]) ? 1.f : 0.f;
        }
        op[320 + lane] = (float)h1 / (float)(c1 ? c1 : 1);
        op[384 + lane] = (float)h2 / (float)(c2 ? c2 : 1);
        op[448 + lane] = (float)h3 / (float)(c3 ? c3 : 1);
        op[512 + lane] = (float)h4 / (float)(c4 ? c4 : 1);
        op[576 + lane] = (float)cu / (float)(q ? q : 1);
        if (lane < 8) {
            float v = 0.f;
            if (lane == 0) v = (float)c1;
            else if (lane == 1) v = (float)c2;
            else if (lane == 2) v = (float)c3;
            else if (lane == 3) v = (float)c4;
            else if (lane == 4) v = (float)q;
            op[640 + lane] = v;
        }
    }
}

extern "C" void kernel_launch(void* const* d_in, const int* in_sizes, int n_in,
                              void* d_out, int out_size, void* d_ws, size_t ws_size,
                              hipStream_t stream) {
    const int* src = (const int*)d_in[0];
    float* out = (float*)d_out;
    char* ws = (char*)d_ws;
    ulonglong2* PAIR = (ulonglong2*)(ws);
    u64* PG   = (u64*)(ws + (256u << 10));
    u16* PB   = (u16*)(ws + (384u << 10));
    u16* PU   = (u16*)(ws + (2432u << 10));
    u16* PS1  = (u16*)(ws + (2464u << 10));
    u32* RB   = (u32*)(ws + (2496u << 10));
    u8*  SRC8 = (u8*)(ws + (2624u << 10));

    k12_build<<<dim3(8, BATCH), 256, 0, stream>>>(src, PAIR, PG, PB, PU, PS1, RB, SRC8);
    k3_compute<<<dim3(256, BATCH), 256, 0, stream>>>(PAIR, PG, PB, PU, PS1, RB, SRC8, out);
}